// Round 1
// baseline (249.531 us; speedup 1.0000x reference)
//
#include <hip/hip_runtime.h>

#define B_  8
#define C_  64
#define T_  12
#define N_  512
#define E_  8192
#define H_  4
#define CO_ 64
#define G_  (B_ * T_)        // 96
#define EP_ (E_ + N_)        // 8704 edges incl self loops
#define MAXDEG 256

// ---------------- K1: h = xg @ W ; a_src, a_dst ----------------
// grid: G_*8 blocks (each: one graph g, 64-node tile), 256 threads.
// thread (lane=n_local, q=head). Each thread computes h[g,n,head,0:64] in regs,
// then the att_src/att_dst dots are thread-local.
__global__ __launch_bounds__(256) void k_gemm(
    const float* __restrict__ x, const float* __restrict__ W,
    const float* __restrict__ att_src, const float* __restrict__ att_dst,
    float* __restrict__ h, float* __restrict__ as_, float* __restrict__ ad_)
{
    __shared__ float xs[64][64];   // [c][n_local], 16 KB
    int bid  = blockIdx.x;
    int g    = bid >> 3, tile = bid & 7;
    int b    = g / T_,   t    = g - b * T_;
    int n0   = tile * 64;
    int tid  = threadIdx.x;
    int lane = tid & 63;
    int hh   = tid >> 6;

    // stage x tile: coalesced over n
    #pragma unroll
    for (int i = 0; i < 16; ++i) {
        int c = (tid >> 6) + i * 4;
        xs[c][lane] = x[((size_t)(b * C_ + c) * T_ + t) * N_ + n0 + lane];
    }
    __syncthreads();

    float acc[64];
    #pragma unroll
    for (int j = 0; j < 64; ++j) acc[j] = 0.f;

    for (int c = 0; c < 64; ++c) {
        float xv = xs[c][lane];
        // wave-uniform W row slice: 16 float4 broadcast loads (L1/L2 hot)
        const float4* w4 = reinterpret_cast<const float4*>(W + c * 256 + hh * 64);
        #pragma unroll
        for (int j4 = 0; j4 < 16; ++j4) {
            float4 w = w4[j4];
            acc[4 * j4 + 0] += xv * w.x;
            acc[4 * j4 + 1] += xv * w.y;
            acc[4 * j4 + 2] += xv * w.z;
            acc[4 * j4 + 3] += xv * w.w;
        }
    }

    // attention dots (thread-local: thread holds full head row)
    const float4* a1 = reinterpret_cast<const float4*>(att_src + hh * 64);
    const float4* a2 = reinterpret_cast<const float4*>(att_dst + hh * 64);
    float s1 = 0.f, s2 = 0.f;
    #pragma unroll
    for (int j4 = 0; j4 < 16; ++j4) {
        float4 u = a1[j4], v = a2[j4];
        s1 += acc[4*j4+0]*u.x + acc[4*j4+1]*u.y + acc[4*j4+2]*u.z + acc[4*j4+3]*u.w;
        s2 += acc[4*j4+0]*v.x + acc[4*j4+1]*v.y + acc[4*j4+2]*v.z + acc[4*j4+3]*v.w;
    }
    int n = n0 + lane;
    as_[(size_t)(g * N_ + n) * H_ + hh] = s1;
    ad_[(size_t)(g * N_ + n) * H_ + hh] = s2;

    float4* hp = reinterpret_cast<float4*>(h + ((size_t)(g * N_ + n) * H_ + hh) * CO_);
    #pragma unroll
    for (int j4 = 0; j4 < 16; ++j4)
        hp[j4] = make_float4(acc[4*j4], acc[4*j4+1], acc[4*j4+2], acc[4*j4+3]);
}

// ---------------- K2: CSR build ----------------
__global__ void k_deg_init(int* cnt) {
    cnt[blockIdx.x * blockDim.x + threadIdx.x] = 1;   // self loop
}
__global__ void k_count(const int* __restrict__ ei, int* cnt) {
    int e = blockIdx.x * blockDim.x + threadIdx.x;    // E_ threads
    atomicAdd(&cnt[ei[E_ + e]], 1);
}
__global__ __launch_bounds__(512) void k_scan(const int* __restrict__ cnt,
                                              int* off, int* cursor) {
    __shared__ int s[512];
    int tid = threadIdx.x;
    int v = cnt[tid];
    s[tid] = v;
    __syncthreads();
    for (int d = 1; d < 512; d <<= 1) {
        int val = (tid >= d) ? s[tid - d] : 0;
        __syncthreads();
        s[tid] += val;
        __syncthreads();
    }
    int incl = s[tid];
    off[tid]    = incl - v;   // exclusive
    cursor[tid] = incl - v;
    if (tid == 511) off[512] = incl;
}
__global__ void k_scatter(const int* __restrict__ ei, int* cursor, int* srclist) {
    int e = blockIdx.x * blockDim.x + threadIdx.x;    // EP_ threads
    if (e < E_) {
        int d = ei[E_ + e];
        int pos = atomicAdd(&cursor[d], 1);
        srclist[pos] = ei[e];
    } else {
        int n = e - E_;
        int pos = atomicAdd(&cursor[n], 1);
        srclist[pos] = n;                              // self loop
    }
}

// ---------------- K3: per-(g,n) softmax + aggregation ----------------
// one wave per (g,n); lane = output channel c in aggregation phase.
__global__ __launch_bounds__(64) void k_aggr(
    const float* __restrict__ h, const float* __restrict__ as_,
    const float* __restrict__ ad_, const float* __restrict__ bias,
    const int* __restrict__ off, const int* __restrict__ srclist,
    float* __restrict__ out_tmp)
{
    __shared__ float wbuf[MAXDEG][H_ + 1];  // padded: stride 5 avoids bank pile-up
    __shared__ int   ssrc[MAXDEG];
    int bid  = blockIdx.x;
    int g    = bid >> 9, n = bid & 511;
    int lane = threadIdx.x;
    int o0   = off[n];
    int deg  = off[n + 1] - o0;

    float adv[H_];
    #pragma unroll
    for (int hh = 0; hh < H_; ++hh) adv[hh] = ad_[(size_t)(g * N_ + n) * H_ + hh];

    // pass 1: logits -> LDS, per-head max
    float mx[H_] = {-1e30f, -1e30f, -1e30f, -1e30f};
    for (int e = lane; e < deg; e += 64) {
        int s = srclist[o0 + e];
        ssrc[e] = s;
        #pragma unroll
        for (int hh = 0; hh < H_; ++hh) {
            float v = as_[(size_t)(g * N_ + s) * H_ + hh] + adv[hh];
            v = v > 0.f ? v : 0.2f * v;                // leaky relu
            wbuf[e][hh] = v;
            mx[hh] = fmaxf(mx[hh], v);
        }
    }
    #pragma unroll
    for (int d = 1; d < 64; d <<= 1) {
        #pragma unroll
        for (int hh = 0; hh < H_; ++hh)
            mx[hh] = fmaxf(mx[hh], __shfl_xor(mx[hh], d, 64));
    }

    // pass 2: exp + per-head sum (same-lane LDS reuse: no barrier needed yet)
    float sm[H_] = {0.f, 0.f, 0.f, 0.f};
    for (int e = lane; e < deg; e += 64) {
        #pragma unroll
        for (int hh = 0; hh < H_; ++hh) {
            float w = __expf(wbuf[e][hh] - mx[hh]);
            wbuf[e][hh] = w;
            sm[hh] += w;
        }
    }
    #pragma unroll
    for (int d = 1; d < 64; d <<= 1) {
        #pragma unroll
        for (int hh = 0; hh < H_; ++hh)
            sm[hh] += __shfl_xor(sm[hh], d, 64);
    }
    float inv[H_];
    #pragma unroll
    for (int hh = 0; hh < H_; ++hh) inv[hh] = 1.f / sm[hh];

    __syncthreads();   // cross-lane LDS visibility for pass 3

    // pass 3: lane = channel; serial over edges, coalesced 256B h reads
    float accO[H_] = {0.f, 0.f, 0.f, 0.f};
    for (int e = 0; e < deg; ++e) {
        int s = ssrc[e];
        const float* hp = &h[(size_t)(g * N_ + s) * H_ * CO_ + lane];
        #pragma unroll
        for (int hh = 0; hh < H_; ++hh) {
            float alpha = wbuf[e][hh] * inv[hh];       // LDS broadcast
            accO[hh] += alpha * hp[hh * CO_];
        }
    }
    float o = 0.25f * (accO[0] + accO[1] + accO[2] + accO[3]) + bias[lane];
    out_tmp[((size_t)g * N_ + n) * CO_ + lane] = o;
}

// ---------------- K4: transpose [G,N,Co] -> [B,Co,T,N] ----------------
__global__ __launch_bounds__(256) void k_trans(const float* __restrict__ out_tmp,
                                               float* __restrict__ out)
{
    __shared__ float tl[64][65];
    int bid  = blockIdx.x;
    int g    = bid >> 3, tile = bid & 7;
    int b    = g / T_,   t    = g - b * T_;
    int n0   = tile * 64;
    int tid  = threadIdx.x;
    int lane = tid & 63, q = tid >> 6;
    #pragma unroll
    for (int i = 0; i < 16; ++i) {
        int nl = q + i * 4;
        tl[nl][lane] = out_tmp[((size_t)g * N_ + n0 + nl) * CO_ + lane];
    }
    __syncthreads();
    #pragma unroll
    for (int i = 0; i < 16; ++i) {
        int c = q + i * 4;
        out[((size_t)(b * CO_ + c) * T_ + t) * N_ + n0 + lane] = tl[lane][c];
    }
}

extern "C" void kernel_launch(void* const* d_in, const int* in_sizes, int n_in,
                              void* d_out, int out_size, void* d_ws, size_t ws_size,
                              hipStream_t stream) {
    const float* x       = (const float*)d_in[0];
    const int*   ei      = (const int*)  d_in[1];
    const float* W       = (const float*)d_in[2];
    const float* att_src = (const float*)d_in[3];
    const float* att_dst = (const float*)d_in[4];
    const float* bias    = (const float*)d_in[5];
    float* out = (float*)d_out;

    char* p = (char*)d_ws;
    float* h       = (float*)p;  p += (size_t)G_ * N_ * H_ * CO_ * sizeof(float); // 50.3 MB
    float* as_     = (float*)p;  p += (size_t)G_ * N_ * H_ * sizeof(float);
    float* ad_     = (float*)p;  p += (size_t)G_ * N_ * H_ * sizeof(float);
    float* out_tmp = (float*)p;  p += (size_t)G_ * N_ * CO_ * sizeof(float);      // 12.6 MB
    int* cnt       = (int*)p;    p += 512 * sizeof(int);
    int* off       = (int*)p;    p += 516 * sizeof(int);
    int* cursor    = (int*)p;    p += 512 * sizeof(int);
    int* srclist   = (int*)p;    p += EP_ * sizeof(int);

    k_gemm   <<<G_ * 8,   256, 0, stream>>>(x, W, att_src, att_dst, h, as_, ad_);
    k_deg_init<<<2,       256, 0, stream>>>(cnt);
    k_count  <<<E_ / 256, 256, 0, stream>>>(ei, cnt);
    k_scan   <<<1,        512, 0, stream>>>(cnt, off, cursor);
    k_scatter<<<EP_ / 256,256, 0, stream>>>(ei, cursor, srclist);
    k_aggr   <<<G_ * N_,  64,  0, stream>>>(h, as_, ad_, bias, off, srclist, out_tmp);
    k_trans  <<<G_ * 8,   256, 0, stream>>>(out_tmp, out);
}

// Round 2
// 190.565 us; speedup vs baseline: 1.3094x; 1.3094x over previous
//
#include <hip/hip_runtime.h>

#define B_  8
#define C_  64
#define T_  12
#define N_  512
#define E_  8192
#define H_  4
#define CO_ 64
#define G_  (B_ * T_)        // 96
#define EP_ (E_ + N_)        // 8704 edges incl self loops
#define MAXDEG 256

typedef __bf16 bf16x8 __attribute__((ext_vector_type(8)));
typedef float  f32x4  __attribute__((ext_vector_type(4)));

static __device__ __forceinline__ unsigned short f2bf(float f) {
    unsigned int u = __float_as_uint(f);
    unsigned int r = (u + 0x7fffu + ((u >> 16) & 1u)) >> 16;   // RNE
    return (unsigned short)r;
}
static __device__ __forceinline__ float bf2f(unsigned short s) {
    return __uint_as_float(((unsigned int)s) << 16);
}

// ---------------- K1: h = xg @ W (3xbf16 MFMA) ; fused a_src/a_dst ----------------
// grid: 768 blocks (g, 64-node tile), 256 threads = 4 waves.
// Each wave computes a 16(M) x 256(N) strip via 16 n-tiles of 16x16x32 MFMA.
// K=64 split into hi/lo bf16; h = Ahi*Whi + Ahi*Wlo + Alo*Whi (6 MFMAs per n-tile).
__global__ __launch_bounds__(256) void k_gemm(
    const float* __restrict__ x, const float* __restrict__ W,
    const float* __restrict__ att_src, const float* __restrict__ att_dst,
    float* __restrict__ h, float* __restrict__ as_, float* __restrict__ ad_)
{
    // A fragments pre-swizzled: [i*2+ks][lane][j]  (i=wave, ks=k-step)
    __shared__ unsigned short Ahi[8][64][8], Alo[8][64][8];          // 8 KB each
    // B fragments pre-swizzled: [ks][ntile][lane][j]
    __shared__ unsigned short Whi[2][16][64][8], Wlo[2][16][64][8];  // 32 KB each

    int bid  = blockIdx.x;
    int g    = bid >> 3, tile = bid & 7;
    int b    = g / T_,   t    = g - b * T_;
    int n0   = tile * 64;
    int tid  = threadIdx.x;

    // ---- stage W (64x256 fp32) into split-B-fragment layout ----
    #pragma unroll
    for (int it = 0; it < 16; ++it) {
        int idx4 = tid + it * 256;          // float4 index
        int flat = idx4 * 4;                // element index
        int k    = flat >> 8;               // 0..63
        int n    = flat & 255;              // multiple of 4
        float4 w = *reinterpret_cast<const float4*>(W + flat);
        int ks2 = k >> 5, q = (k >> 3) & 3, j = k & 7;
        int nt  = n >> 4,  nl = n & 15;
        int l   = q * 16 + nl;
        float wv[4] = {w.x, w.y, w.z, w.w};
        #pragma unroll
        for (int u = 0; u < 4; ++u) {
            unsigned short hi = f2bf(wv[u]);
            unsigned short lo = f2bf(wv[u] - bf2f(hi));
            Whi[ks2][nt][l + u][j] = hi;
            Wlo[ks2][nt][l + u][j] = lo;
        }
    }

    // ---- stage x tile (64 nodes x 64 ch) into split-A-fragment layout ----
    #pragma unroll
    for (int it = 0; it < 4; ++it) {
        int idx4 = tid + it * 256;
        int flat = idx4 * 4;
        int c    = flat >> 6;               // 0..63
        int nl4  = flat & 63;               // multiple of 4
        float4 xv = *reinterpret_cast<const float4*>(
            x + ((size_t)(b * C_ + c) * T_ + t) * N_ + n0 + nl4);
        int ks = c >> 5, q = (c >> 3) & 3, j = c & 7;
        float vv[4] = {xv.x, xv.y, xv.z, xv.w};
        #pragma unroll
        for (int u = 0; u < 4; ++u) {
            int m = nl4 + u;
            int i = m >> 4, mlow = m & 15;
            int l = q * 16 + mlow;
            unsigned short hi = f2bf(vv[u]);
            unsigned short lo = f2bf(vv[u] - bf2f(hi));
            Ahi[i * 2 + ks][l][j] = hi;
            Alo[i * 2 + ks][l][j] = lo;
        }
    }
    __syncthreads();

    int i   = tid >> 6;       // wave
    int l   = tid & 63;
    int q   = l >> 4;
    int c0  = l & 15;

    bf16x8 ahi0 = *reinterpret_cast<bf16x8*>(&Ahi[i * 2 + 0][l][0]);
    bf16x8 ahi1 = *reinterpret_cast<bf16x8*>(&Ahi[i * 2 + 1][l][0]);
    bf16x8 alo0 = *reinterpret_cast<bf16x8*>(&Alo[i * 2 + 0][l][0]);
    bf16x8 alo1 = *reinterpret_cast<bf16x8*>(&Alo[i * 2 + 1][l][0]);

    float ps1[4][4], ps2[4][4];
    #pragma unroll
    for (int r = 0; r < 4; ++r)
        #pragma unroll
        for (int hh = 0; hh < 4; ++hh) { ps1[r][hh] = 0.f; ps2[r][hh] = 0.f; }

    #pragma unroll
    for (int nt = 0; nt < 16; ++nt) {
        bf16x8 bhi0 = *reinterpret_cast<bf16x8*>(&Whi[0][nt][l][0]);
        bf16x8 bhi1 = *reinterpret_cast<bf16x8*>(&Whi[1][nt][l][0]);
        bf16x8 blo0 = *reinterpret_cast<bf16x8*>(&Wlo[0][nt][l][0]);
        bf16x8 blo1 = *reinterpret_cast<bf16x8*>(&Wlo[1][nt][l][0]);
        f32x4 acc = {0.f, 0.f, 0.f, 0.f};
        acc = __builtin_amdgcn_mfma_f32_16x16x32_bf16(ahi0, bhi0, acc, 0, 0, 0);
        acc = __builtin_amdgcn_mfma_f32_16x16x32_bf16(ahi1, bhi1, acc, 0, 0, 0);
        acc = __builtin_amdgcn_mfma_f32_16x16x32_bf16(ahi0, blo0, acc, 0, 0, 0);
        acc = __builtin_amdgcn_mfma_f32_16x16x32_bf16(ahi1, blo1, acc, 0, 0, 0);
        acc = __builtin_amdgcn_mfma_f32_16x16x32_bf16(alo0, bhi0, acc, 0, 0, 0);
        acc = __builtin_amdgcn_mfma_f32_16x16x32_bf16(alo1, bhi1, acc, 0, 0, 0);

        int hh  = nt >> 2;
        int col = nt * 16 + c0;
        float aS = att_src[hh * 64 + (col & 63)];
        float aD = att_dst[hh * 64 + (col & 63)];
        #pragma unroll
        for (int r = 0; r < 4; ++r) {
            int row = i * 16 + q * 4 + r;
            h[(size_t)(g * N_ + n0 + row) * 256 + col] = acc[r];
            ps1[r][hh] += acc[r] * aS;
            ps2[r][hh] += acc[r] * aD;
        }
    }

    // reduce partial dots over the 16 lanes sharing a row group (same q)
    #pragma unroll
    for (int d = 1; d < 16; d <<= 1) {
        #pragma unroll
        for (int r = 0; r < 4; ++r)
            #pragma unroll
            for (int hh = 0; hh < 4; ++hh) {
                ps1[r][hh] += __shfl_xor(ps1[r][hh], d, 64);
                ps2[r][hh] += __shfl_xor(ps2[r][hh], d, 64);
            }
    }
    if (c0 < H_) {
        #pragma unroll
        for (int r = 0; r < 4; ++r) {
            int row = i * 16 + q * 4 + r;
            float v1 = c0 == 0 ? ps1[r][0] : c0 == 1 ? ps1[r][1] : c0 == 2 ? ps1[r][2] : ps1[r][3];
            float v2 = c0 == 0 ? ps2[r][0] : c0 == 1 ? ps2[r][1] : c0 == 2 ? ps2[r][2] : ps2[r][3];
            as_[(size_t)(g * N_ + n0 + row) * H_ + c0] = v1;
            ad_[(size_t)(g * N_ + n0 + row) * H_ + c0] = v2;
        }
    }
}

// ---------------- K2: CSR build ----------------
__global__ void k_deg_init(int* cnt) {
    cnt[blockIdx.x * blockDim.x + threadIdx.x] = 1;   // self loop
}
__global__ void k_count(const int* __restrict__ ei, int* cnt) {
    int e = blockIdx.x * blockDim.x + threadIdx.x;    // E_ threads
    atomicAdd(&cnt[ei[E_ + e]], 1);
}
__global__ __launch_bounds__(512) void k_scan(const int* __restrict__ cnt,
                                              int* off, int* cursor) {
    __shared__ int s[512];
    int tid = threadIdx.x;
    int v = cnt[tid];
    s[tid] = v;
    __syncthreads();
    for (int d = 1; d < 512; d <<= 1) {
        int val = (tid >= d) ? s[tid - d] : 0;
        __syncthreads();
        s[tid] += val;
        __syncthreads();
    }
    int incl = s[tid];
    off[tid]    = incl - v;   // exclusive
    cursor[tid] = incl - v;
    if (tid == 511) off[512] = incl;
}
__global__ void k_scatter(const int* __restrict__ ei, int* cursor, int* srclist) {
    int e = blockIdx.x * blockDim.x + threadIdx.x;    // EP_ threads
    if (e < E_) {
        int d = ei[E_ + e];
        int pos = atomicAdd(&cursor[d], 1);
        srclist[pos] = ei[e];
    } else {
        int n = e - E_;
        int pos = atomicAdd(&cursor[n], 1);
        srclist[pos] = n;                              // self loop
    }
}

// ---------------- K3: per-(g,n) softmax + aggregation ----------------
// 256-thread blocks, one (g,n) per wave (4 nodes per block).
__global__ __launch_bounds__(256) void k_aggr(
    const float* __restrict__ h, const float* __restrict__ as_,
    const float* __restrict__ ad_, const float* __restrict__ bias,
    const int* __restrict__ off, const int* __restrict__ srclist,
    float* __restrict__ out_tmp)
{
    __shared__ float wbuf[4][MAXDEG][H_ + 1];
    __shared__ int   ssrc[4][MAXDEG];
    int wave = threadIdx.x >> 6;
    int lane = threadIdx.x & 63;
    int idx  = blockIdx.x * 4 + wave;
    int g    = idx >> 9, n = idx & 511;
    int o0   = off[n];
    int deg  = off[n + 1] - o0;

    float4 adv = *reinterpret_cast<const float4*>(&ad_[(size_t)(g * N_ + n) * H_]);

    // pass 1: logits -> LDS, per-head max
    float mx[H_] = {-1e30f, -1e30f, -1e30f, -1e30f};
    for (int e = lane; e < deg; e += 64) {
        int s = srclist[o0 + e];
        ssrc[wave][e] = s;
        float4 av = *reinterpret_cast<const float4*>(&as_[(size_t)(g * N_ + s) * H_]);
        float vv[4] = {av.x + adv.x, av.y + adv.y, av.z + adv.z, av.w + adv.w};
        #pragma unroll
        for (int hh = 0; hh < H_; ++hh) {
            float v = vv[hh];
            v = v > 0.f ? v : 0.2f * v;                // leaky relu
            wbuf[wave][e][hh] = v;
            mx[hh] = fmaxf(mx[hh], v);
        }
    }
    #pragma unroll
    for (int d = 1; d < 64; d <<= 1) {
        #pragma unroll
        for (int hh = 0; hh < H_; ++hh)
            mx[hh] = fmaxf(mx[hh], __shfl_xor(mx[hh], d, 64));
    }

    // pass 2: exp + per-head sum (same-lane LDS reuse)
    float sm[H_] = {0.f, 0.f, 0.f, 0.f};
    for (int e = lane; e < deg; e += 64) {
        #pragma unroll
        for (int hh = 0; hh < H_; ++hh) {
            float w = __expf(wbuf[wave][e][hh] - mx[hh]);
            wbuf[wave][e][hh] = w;
            sm[hh] += w;
        }
    }
    #pragma unroll
    for (int d = 1; d < 64; d <<= 1) {
        #pragma unroll
        for (int hh = 0; hh < H_; ++hh)
            sm[hh] += __shfl_xor(sm[hh], d, 64);
    }
    float inv[H_];
    #pragma unroll
    for (int hh = 0; hh < H_; ++hh) inv[hh] = 1.f / sm[hh];

    __syncthreads();   // cross-lane LDS visibility for pass 3

    // pass 3: lane = channel; serial over edges, coalesced 256B h reads
    float accO[H_] = {0.f, 0.f, 0.f, 0.f};
    for (int e = 0; e < deg; ++e) {
        int s = ssrc[wave][e];
        const float* hp = &h[(size_t)(g * N_ + s) * H_ * CO_ + lane];
        #pragma unroll
        for (int hh = 0; hh < H_; ++hh) {
            float alpha = wbuf[wave][e][hh] * inv[hh];  // LDS broadcast
            accO[hh] += alpha * hp[hh * CO_];
        }
    }
    float o = 0.25f * (accO[0] + accO[1] + accO[2] + accO[3]) + bias[lane];
    out_tmp[((size_t)g * N_ + n) * CO_ + lane] = o;
}

// ---------------- K4: transpose [G,N,Co] -> [B,Co,T,N] ----------------
__global__ __launch_bounds__(256) void k_trans(const float* __restrict__ out_tmp,
                                               float* __restrict__ out)
{
    __shared__ float tl[64][65];
    int bid  = blockIdx.x;
    int g    = bid >> 3, tile = bid & 7;
    int b    = g / T_,   t    = g - b * T_;
    int n0   = tile * 64;
    int tid  = threadIdx.x;
    int lane = tid & 63, qq = tid >> 6;
    #pragma unroll
    for (int i = 0; i < 16; ++i) {
        int nl = qq + i * 4;
        tl[nl][lane] = out_tmp[((size_t)g * N_ + n0 + nl) * CO_ + lane];
    }
    __syncthreads();
    #pragma unroll
    for (int i = 0; i < 16; ++i) {
        int c = qq + i * 4;
        out[((size_t)(b * CO_ + c) * T_ + t) * N_ + n0 + lane] = tl[lane][c];
    }
}

extern "C" void kernel_launch(void* const* d_in, const int* in_sizes, int n_in,
                              void* d_out, int out_size, void* d_ws, size_t ws_size,
                              hipStream_t stream) {
    const float* x       = (const float*)d_in[0];
    const int*   ei      = (const int*)  d_in[1];
    const float* W       = (const float*)d_in[2];
    const float* att_src = (const float*)d_in[3];
    const float* att_dst = (const float*)d_in[4];
    const float* bias    = (const float*)d_in[5];
    float* out = (float*)d_out;

    char* p = (char*)d_ws;
    float* h       = (float*)p;  p += (size_t)G_ * N_ * H_ * CO_ * sizeof(float); // 50.3 MB
    float* as_     = (float*)p;  p += (size_t)G_ * N_ * H_ * sizeof(float);
    float* ad_     = (float*)p;  p += (size_t)G_ * N_ * H_ * sizeof(float);
    float* out_tmp = (float*)p;  p += (size_t)G_ * N_ * CO_ * sizeof(float);      // 12.6 MB
    int* cnt       = (int*)p;    p += 512 * sizeof(int);
    int* off       = (int*)p;    p += 516 * sizeof(int);
    int* cursor    = (int*)p;    p += 512 * sizeof(int);
    int* srclist   = (int*)p;    p += EP_ * sizeof(int);

    k_gemm   <<<G_ * 8,     256, 0, stream>>>(x, W, att_src, att_dst, h, as_, ad_);
    k_deg_init<<<2,         256, 0, stream>>>(cnt);
    k_count  <<<E_ / 256,   256, 0, stream>>>(ei, cnt);
    k_scan   <<<1,          512, 0, stream>>>(cnt, off, cursor);
    k_scatter<<<EP_ / 256,  256, 0, stream>>>(ei, cursor, srclist);
    k_aggr   <<<G_ * N_ / 4, 256, 0, stream>>>(h, as_, ad_, bias, off, srclist, out_tmp);
    k_trans  <<<G_ * 8,     256, 0, stream>>>(out_tmp, out);
}

// Round 3
// 173.993 us; speedup vs baseline: 1.4341x; 1.0952x over previous
//
#include <hip/hip_runtime.h>

#define B_  8
#define C_  64
#define T_  12
#define N_  512
#define E_  8192
#define H_  4
#define CO_ 64
#define G_  (B_ * T_)        // 96
#define EP_ (E_ + N_)        // 8704 edges incl self loops
#define MAXDEG 256

typedef __bf16 bf16x8 __attribute__((ext_vector_type(8)));
typedef unsigned short usx8 __attribute__((ext_vector_type(8)));
typedef float  f32x4  __attribute__((ext_vector_type(4)));

static __device__ __forceinline__ unsigned short f2bf(float f) {
    unsigned int u = __float_as_uint(f);
    return (unsigned short)((u + 0x7fffu + ((u >> 16) & 1u)) >> 16);   // RNE
}
static __device__ __forceinline__ float bf2f(unsigned short s) {
    return __uint_as_float(((unsigned int)s) << 16);
}

// ---------------- K0: Wsrc[c,h] = W[c,h*64:]·att_src[h,:], same for dst ----------
__global__ __launch_bounds__(256) void k_wred(
    const float* __restrict__ W, const float* __restrict__ att_src,
    const float* __restrict__ att_dst, float* __restrict__ Wsrc, float* __restrict__ Wdst)
{
    int tid = threadIdx.x;
    int c = tid & 63, hh = tid >> 6;
    float s1 = 0.f, s2 = 0.f;
    for (int co = 0; co < 64; ++co) {
        float w = W[c * 256 + hh * 64 + co];
        s1 += w * att_src[hh * 64 + co];
        s2 += w * att_dst[hh * 64 + co];
    }
    Wsrc[c * 4 + hh] = s1;
    Wdst[c * 4 + hh] = s2;
}

// ---------------- K1: xt[g,n,c] transpose + as_/ad_ = xt·Wsrc/Wdst (exact fp32) --
__global__ __launch_bounds__(256) void k_prep(
    const float* __restrict__ x, const float* __restrict__ Wsrc,
    const float* __restrict__ Wdst,
    float* __restrict__ xt, float* __restrict__ as_, float* __restrict__ ad_)
{
    __shared__ float xs[64][65];
    int bid  = blockIdx.x;                 // 768
    int g    = bid >> 3, tile = bid & 7;
    int b    = g / T_,   t    = g - b * T_;
    int n0   = tile * 64;
    int tid  = threadIdx.x;
    int lane = tid & 63, q = tid >> 6;

    #pragma unroll
    for (int i = 0; i < 16; ++i) {
        int c = q + i * 4;
        xs[c][lane] = x[((size_t)(b * C_ + c) * T_ + t) * N_ + n0 + lane];
    }
    __syncthreads();

    // wave q computes head-q logit dots, lane = node
    float s1 = 0.f, s2 = 0.f;
    for (int c = 0; c < 64; ++c) {
        float v = xs[c][lane];
        s1 += v * Wsrc[c * 4 + q];
        s2 += v * Wdst[c * 4 + q];
    }
    as_[(size_t)(g * N_ + n0 + lane) * H_ + q] = s1;
    ad_[(size_t)(g * N_ + n0 + lane) * H_ + q] = s2;

    // write xt[node][c], coalesced over c
    #pragma unroll
    for (int i = 0; i < 16; ++i) {
        int nl = q + i * 4;
        xt[((size_t)(g * N_ + n0 + nl)) * 64 + lane] = xs[lane][nl];
    }
}

// ---------------- K2: CSR build ----------------
__global__ void k_deg_init(int* cnt) {
    cnt[blockIdx.x * blockDim.x + threadIdx.x] = 1;   // self loop
}
__global__ void k_count(const int* __restrict__ ei, int* cnt) {
    int e = blockIdx.x * blockDim.x + threadIdx.x;
    atomicAdd(&cnt[ei[E_ + e]], 1);
}
__global__ __launch_bounds__(512) void k_scan(const int* __restrict__ cnt,
                                              int* off, int* cursor) {
    __shared__ int s[512];
    int tid = threadIdx.x;
    int v = cnt[tid];
    s[tid] = v;
    __syncthreads();
    for (int d = 1; d < 512; d <<= 1) {
        int val = (tid >= d) ? s[tid - d] : 0;
        __syncthreads();
        s[tid] += val;
        __syncthreads();
    }
    int incl = s[tid];
    off[tid]    = incl - v;
    cursor[tid] = incl - v;
    if (tid == 511) off[512] = incl;
}
__global__ void k_scatter(const int* __restrict__ ei, int* cursor, int* srclist) {
    int e = blockIdx.x * blockDim.x + threadIdx.x;
    if (e < E_) {
        int d = ei[E_ + e];
        int pos = atomicAdd(&cursor[d], 1);
        srclist[pos] = ei[e];
    } else {
        int n = e - E_;
        int pos = atomicAdd(&cursor[n], 1);
        srclist[pos] = n;
    }
}

// ---------------- K3: softmax + aggregate x into z[g,n,h,0:64] ----------------
// XCD-swizzled: blockIdx%8 -> XCD j handles graphs [12j,12j+12): per-XCD L2
// working set = 12 * 128 KB xt slices = 1.5 MB (fits 4 MB L2).
__global__ __launch_bounds__(256) void k_aggr(
    const float* __restrict__ xt, const float* __restrict__ as_,
    const float* __restrict__ ad_,
    const int* __restrict__ off, const int* __restrict__ srclist,
    float* __restrict__ z)
{
    __shared__ float wbuf[4][MAXDEG][H_ + 1];
    __shared__ int   ssrc[4][MAXDEG];
    int wave = threadIdx.x >> 6;
    int lane = threadIdx.x & 63;
    int xcd  = blockIdx.x & 7, slot = blockIdx.x >> 3;
    int g    = xcd * 12 + (slot >> 7);
    int n    = (slot & 127) * 4 + wave;
    int o0   = off[n];
    int deg  = off[n + 1] - o0;

    float4 adv = *reinterpret_cast<const float4*>(&ad_[(size_t)(g * N_ + n) * H_]);

    float mx[H_] = {-1e30f, -1e30f, -1e30f, -1e30f};
    for (int e = lane; e < deg; e += 64) {
        int s = srclist[o0 + e];
        ssrc[wave][e] = s;
        float4 av = *reinterpret_cast<const float4*>(&as_[(size_t)(g * N_ + s) * H_]);
        float vv[4] = {av.x + adv.x, av.y + adv.y, av.z + adv.z, av.w + adv.w};
        #pragma unroll
        for (int hh = 0; hh < H_; ++hh) {
            float v = vv[hh];
            v = v > 0.f ? v : 0.2f * v;
            wbuf[wave][e][hh] = v;
            mx[hh] = fmaxf(mx[hh], v);
        }
    }
    #pragma unroll
    for (int d = 1; d < 64; d <<= 1)
        #pragma unroll
        for (int hh = 0; hh < H_; ++hh)
            mx[hh] = fmaxf(mx[hh], __shfl_xor(mx[hh], d, 64));

    float sm[H_] = {0.f, 0.f, 0.f, 0.f};
    for (int e = lane; e < deg; e += 64) {
        #pragma unroll
        for (int hh = 0; hh < H_; ++hh) {
            float w = __expf(wbuf[wave][e][hh] - mx[hh]);
            wbuf[wave][e][hh] = w;
            sm[hh] += w;
        }
    }
    #pragma unroll
    for (int d = 1; d < 64; d <<= 1)
        #pragma unroll
        for (int hh = 0; hh < H_; ++hh)
            sm[hh] += __shfl_xor(sm[hh], d, 64);
    float inv[H_];
    #pragma unroll
    for (int hh = 0; hh < H_; ++hh) inv[hh] = 1.f / sm[hh];

    // pre-scale alphas so pass 3 is pure FMA
    for (int e = lane; e < deg; e += 64) {
        #pragma unroll
        for (int hh = 0; hh < H_; ++hh)
            wbuf[wave][e][hh] *= inv[hh];
    }
    __syncthreads();

    // pass 3: lane = x-channel; gather 256B xt rows (L2-hot)
    float z0 = 0.f, z1 = 0.f, z2 = 0.f, z3 = 0.f;
    for (int e = 0; e < deg; ++e) {
        int s = ssrc[wave][e];
        float xv = xt[((size_t)(g * N_ + s)) * 64 + lane];
        z0 += wbuf[wave][e][0] * xv;
        z1 += wbuf[wave][e][1] * xv;
        z2 += wbuf[wave][e][2] * xv;
        z3 += wbuf[wave][e][3] * xv;
    }
    size_t base = ((size_t)(g * N_ + n)) * 256;
    z[base +   0 + lane] = z0;
    z[base +  64 + lane] = z1;
    z[base + 128 + lane] = z2;
    z[base + 192 + lane] = z3;
}

// ---------------- K4: out = 0.25*z@Wcat + bias, fused transpose to [B,Co,T,N] ----
// Wcat[k=h*64+c][co] = W[c][h*64+co]; 3-term split-bf16 MFMA.
__global__ __launch_bounds__(256) void k_out(
    const float* __restrict__ z, const float* __restrict__ W,
    const float* __restrict__ bias, float* __restrict__ out)
{
    __shared__ char lds[65536];
    unsigned short (*Bhi)[4][64][8] = (unsigned short (*)[4][64][8])lds;            // 32KB
    unsigned short (*Blo)[4][64][8] = (unsigned short (*)[4][64][8])(lds + 32768);  // 32KB
    float (*tl)[65] = (float (*)[65])lds;   // aliases Bhi AFTER k-loop barrier

    int bid  = blockIdx.x;                 // 768
    int g    = bid >> 3, tile = bid & 7;
    int b    = g / T_,   t    = g - b * T_;
    int n0   = tile * 64;
    int tid  = threadIdx.x;

    // stage W into split B-fragment layout: k = h*64+c
    #pragma unroll
    for (int it = 0; it < 16; ++it) {
        int flat = (tid + it * 256) * 4;
        int c  = flat >> 8, r = flat & 255;
        int hh = r >> 6,   co = r & 63;
        float4 w = *reinterpret_cast<const float4*>(W + flat);
        int ks = hh * 2 + (c >> 5), kq = (c >> 3) & 3, j = c & 7;
        int nt = co >> 4, l0 = kq * 16 + (co & 15);
        float wv[4] = {w.x, w.y, w.z, w.w};
        #pragma unroll
        for (int u = 0; u < 4; ++u) {
            unsigned short hi = f2bf(wv[u]);
            Bhi[ks][nt][l0 + u][j] = hi;
            Blo[ks][nt][l0 + u][j] = f2bf(wv[u] - bf2f(hi));
        }
    }
    __syncthreads();

    int i = tid >> 6, l = tid & 63;
    int m = l & 15, quad = l >> 4;
    const float* zrow = z + ((size_t)(g * N_) + n0 + i * 16 + m) * 256 + quad * 8;

    f32x4 acc[4];
    #pragma unroll
    for (int nt = 0; nt < 4; ++nt) acc[nt] = (f32x4){0.f, 0.f, 0.f, 0.f};

    #pragma unroll
    for (int ks = 0; ks < 8; ++ks) {
        float av[8];
        *reinterpret_cast<float4*>(&av[0]) = *reinterpret_cast<const float4*>(zrow + ks * 32);
        *reinterpret_cast<float4*>(&av[4]) = *reinterpret_cast<const float4*>(zrow + ks * 32 + 4);
        usx8 uhi, ulo;
        #pragma unroll
        for (int j = 0; j < 8; ++j) {
            unsigned short hi = f2bf(av[j]);
            uhi[j] = hi;
            ulo[j] = f2bf(av[j] - bf2f(hi));
        }
        bf16x8 ahi = __builtin_bit_cast(bf16x8, uhi);
        bf16x8 alo = __builtin_bit_cast(bf16x8, ulo);
        #pragma unroll
        for (int nt = 0; nt < 4; ++nt) {
            bf16x8 bh = *reinterpret_cast<bf16x8*>(&Bhi[ks][nt][l][0]);
            bf16x8 bl = *reinterpret_cast<bf16x8*>(&Blo[ks][nt][l][0]);
            acc[nt] = __builtin_amdgcn_mfma_f32_16x16x32_bf16(ahi, bh, acc[nt], 0, 0, 0);
            acc[nt] = __builtin_amdgcn_mfma_f32_16x16x32_bf16(ahi, bl, acc[nt], 0, 0, 0);
            acc[nt] = __builtin_amdgcn_mfma_f32_16x16x32_bf16(alo, bh, acc[nt], 0, 0, 0);
        }
    }
    __syncthreads();   // B reads done; safe to alias tl

    #pragma unroll
    for (int nt = 0; nt < 4; ++nt) {
        int co = nt * 16 + m;               // D col = lane&15
        float bv = bias[co];
        #pragma unroll
        for (int r = 0; r < 4; ++r) {
            int row = i * 16 + quad * 4 + r; // D row = (lane>>4)*4+reg
            tl[row][co] = 0.25f * acc[nt][r] + bv;
        }
    }
    __syncthreads();

    #pragma unroll
    for (int it = 0; it < 16; ++it) {
        int c = i + it * 4;
        out[((size_t)(b * CO_ + c) * T_ + t) * N_ + n0 + l] = tl[l][c];
    }
}

extern "C" void kernel_launch(void* const* d_in, const int* in_sizes, int n_in,
                              void* d_out, int out_size, void* d_ws, size_t ws_size,
                              hipStream_t stream) {
    const float* x       = (const float*)d_in[0];
    const int*   ei      = (const int*)  d_in[1];
    const float* W       = (const float*)d_in[2];
    const float* att_src = (const float*)d_in[3];
    const float* att_dst = (const float*)d_in[4];
    const float* bias    = (const float*)d_in[5];
    float* out = (float*)d_out;

    char* p = (char*)d_ws;
    float* z       = (float*)p;  p += (size_t)G_ * N_ * H_ * CO_ * sizeof(float); // 50.3 MB
    float* xt      = (float*)p;  p += (size_t)G_ * N_ * C_ * sizeof(float);       // 12.6 MB
    float* as_     = (float*)p;  p += (size_t)G_ * N_ * H_ * sizeof(float);
    float* ad_     = (float*)p;  p += (size_t)G_ * N_ * H_ * sizeof(float);
    float* Wsrc    = (float*)p;  p += C_ * H_ * sizeof(float);
    float* Wdst    = (float*)p;  p += C_ * H_ * sizeof(float);
    int* cnt       = (int*)p;    p += 512 * sizeof(int);
    int* off       = (int*)p;    p += 516 * sizeof(int);
    int* cursor    = (int*)p;    p += 512 * sizeof(int);
    int* srclist   = (int*)p;    p += EP_ * sizeof(int);

    k_wred    <<<1,          256, 0, stream>>>(W, att_src, att_dst, Wsrc, Wdst);
    k_prep    <<<G_ * 8,     256, 0, stream>>>(x, Wsrc, Wdst, xt, as_, ad_);
    k_deg_init<<<2,          256, 0, stream>>>(cnt);
    k_count   <<<E_ / 256,   256, 0, stream>>>(ei, cnt);
    k_scan    <<<1,          512, 0, stream>>>(cnt, off, cursor);
    k_scatter <<<EP_ / 256,  256, 0, stream>>>(ei, cursor, srclist);
    k_aggr    <<<G_ * N_ / 4, 256, 0, stream>>>(xt, as_, ad_, off, srclist, z);
    k_out     <<<G_ * 8,     256, 0, stream>>>(z, W, bias, out);
}